// Round 19
// baseline (105.010 us; speedup 1.0000x reference)
//
#include <hip/hip_runtime.h>
#include <math.h>

// Problem constants (fixed by reference: B=32, 32x32 tokens, DM=768, C=64, ch=32,
// theta_res=3 -> 60 thetas, rho_res=1 on 32x32 -> q=44 -> 89 rhos)
#define NB    32
#define NTOK  1024
#define DMODEL 768
#define CF    64
#define CHH   32
#define NRHO  89
#define NTH   60
#define HRB   (NRHO*NTH)  // 5340

typedef short bf16x8 __attribute__((ext_vector_type(8)));
typedef float f32x4  __attribute__((ext_vector_type(4)));
typedef unsigned int uint;
typedef unsigned short ushort;
typedef unsigned char uchar;

__device__ __forceinline__ ushort f2bf(float f) {
    uint u = __float_as_uint(f);
    return (ushort)((u + 0x7FFF + ((u >> 16) & 1)) >> 16);
}
__device__ __forceinline__ float bf2f(ushort u) {
    return __uint_as_float(((uint)u) << 16);
}
// HW packed convert: dst[15:0]=bf16(lo), dst[31:16]=bf16(hi). RTNE, same as f2bf.
__device__ __forceinline__ uint cvtpk(float lo, float hi) {
    uint r;
    asm("v_cvt_pk_bf16_f32 %0, %1, %2" : "=v"(r) : "v"(lo), "v"(hi));
    return r;
}

#define GLDS16(gp, lp) __builtin_amdgcn_global_load_lds( \
    (const __attribute__((address_space(1))) unsigned int*)(gp), \
    (__attribute__((address_space(3))) unsigned int*)(lp), 16, 0, 0)

// ---------------------------------------------------------------------------
// K0 mega-kernel (unchanged):
//  blocks 0..59    : per-theta CSR (counting sort) + rho8[t][n] byte table
//  blocks 60..155  : Wcat = [Wt_in; W1@Wt_in] -> bf16 tiled, bcat
//  blocks 156..215 : Wt_out -> wout tiled; W2 -> w2t MFMA A-frags
__global__ __launch_bounds__(256) void k0_prep(
    int* __restrict__ perm, int* __restrict__ rowptr, uchar* __restrict__ rho8,
    const float* __restrict__ Wt_in, const float* __restrict__ bt_in,
    const float* __restrict__ W1, short* __restrict__ wcat,
    float* __restrict__ bcat,
    const float* __restrict__ Wt_out, const float* __restrict__ W2,
    short* __restrict__ wout, short* __restrict__ w2t) {
    __shared__ int rho_n[NTOK];
    __shared__ int cnt2[64 * 90];
    __shared__ int tot[96];
    __shared__ int base[96];
    __shared__ float w1row[64];
    const int tid = threadIdx.x;
    const int blk = blockIdx.x;

    if (blk < 60) {
        const int t = blk;
        const double rad = ((double)(t * 3)) * (M_PI / 180.0);
        const double ct = cos(rad), st = sin(rad);
        for (int n = tid; n < NTOK; n += 256) {
            int i = n >> 5, j = n & 31;
            double rho = (double)(j - 16) * ct + (double)(16 - i) * st;
            int ridx = (int)rint(rho) + 44;
            rho_n[n] = ridx;
            rho8[t * NTOK + n] = (uchar)ridx;
        }
        for (int i = tid; i < 64 * 90; i += 256) cnt2[i] = 0;
        __syncthreads();
        for (int n = tid; n < NTOK; n += 256)
            atomicAdd(&cnt2[(n >> 4) * 90 + rho_n[n]], 1);
        __syncthreads();
        if (tid < NRHO) {
            int s = 0;
            for (int c = 0; c < 64; ++c) {
                int v = cnt2[c * 90 + tid];
                cnt2[c * 90 + tid] = s;
                s += v;
            }
            tot[tid] = s;
        }
        __syncthreads();
        if (tid == 0) {
            int s = 0;
            for (int r = 0; r < NRHO; ++r) { base[r] = s; s += tot[r]; }
            base[NRHO] = s;
        }
        __syncthreads();
        if (tid < NRHO + 1) rowptr[t * 90 + tid] = base[tid];
        if (tid < 64) {
            const int c = tid;
            #pragma unroll
            for (int j = 0; j < 16; ++j) {
                int n = c * 16 + j;
                int r = rho_n[n];
                int cur = cnt2[c * 90 + r];
                cnt2[c * 90 + r] = cur + 1;
                perm[t * NTOK + base[r] + cur] = n;
            }
        }
    } else if (blk < 156) {
        const int c = blk - 60;   // 0..95
        if (c >= 64)
            for (int j = tid; j < 64; j += 256) w1row[j] = W1[(c - 64) * 64 + j];
        __syncthreads();
        for (int k = tid; k < DMODEL; k += 256) {
            float v;
            if (c < 64) v = Wt_in[c * DMODEL + k];
            else {
                v = 0.0f;
                for (int j = 0; j < 64; ++j) v += w1row[j] * Wt_in[j * DMODEL + k];
            }
            int kt = k >> 6, kk = k & 63;
            wcat[(((kt << 3) + (kk >> 3)) * 96 + c) * 8 + (k & 7)] = (short)f2bf(v);
        }
        if (tid == 0) {
            float bv;
            if (c < 64) bv = bt_in[c];
            else {
                bv = 0.0f;
                for (int j = 0; j < 64; ++j) bv += W1[(c - 64) * 64 + j] * bt_in[j];
            }
            bcat[c] = bv;
        }
    } else {
        int idx = (blk - 156) * 256 + tid;   // 15360 total
        if (idx < 6144) {
            int d = idx >> 3, kg = idx & 7;
            float4 a = *(const float4*)&Wt_out[d * 64 + kg * 8];
            float4 b = *(const float4*)&Wt_out[d * 64 + kg * 8 + 4];
            uint4 v = make_uint4(cvtpk(a.x, a.y), cvtpk(a.z, a.w),
                                 cvtpk(b.x, b.y), cvtpk(b.z, b.w));
            *(uint4*)&wout[(((d >> 7) * 8 + kg) * 128 + (d & 127)) * 8] = v;
        } else if (idx < 6144 + 9216) {
            int q = idx - 6144;
            int e = q & 7, ln = (q >> 3) & 63, wm = (q >> 9) & 1, k = q >> 10;
            int o = wm * 16 + (ln & 15), i = ((ln >> 4) << 3) + e;
            w2t[q] = (short)f2bf(W2[(o * 32 + i) * 9 + k]);
        }
    }
}

// ---------------------------------------------------------------------------
// K1 v9: GLDS-staged MFMA GEMM with BK=128 -> only 6 barrier-drains (vs 12).
// 256 thr, 32-row tiles, grid 1024. LDS 64 KB (A 2x8 KB + B 2x24 KB dbuf)
// -> 2 blocks/CU (proven irrelevant for this kernel: r10 == r17).
// [feat|y] = tokens @ Wcat^T + bcat.
__global__ __launch_bounds__(256, 2) void k1_mfma(
    const float* __restrict__ tokens, const short* __restrict__ wcat,
    const float* __restrict__ bcat, ushort* __restrict__ featb,
    ushort* __restrict__ ybb) {
    __shared__ __align__(16) short Asm[2][4096];    // [kg16][m32][k8], 8 KB each
    __shared__ __align__(16) short Bsm[2][12288];   // [kg16][c96][k8], 24 KB each

    const int tid = threadIdx.x;
    const int lane = tid & 63, wave = tid >> 6;
    const int wm = wave >> 1, wn = wave & 1;        // wm 0..1 (16 rows), wn 0..1
    const int row0 = blockIdx.x * 32;
    const int l15 = lane & 15, lq = lane >> 4;
    const int sm = tid >> 3, sq = tid & 7;          // staging: 32 rows x 8 groups

    // each staging thread covers k = sq*16 .. sq*16+15 of its row per step
    const float* arow = tokens + (size_t)(row0 + sm) * DMODEL + sq * 16;

    f32x4 acc[3] = {};
    float4 ta0, ta1, ta2, ta3;

    // prologue: stage step 0 (global k 0..127)
    ta0 = *(const float4*)&arow[0];  ta1 = *(const float4*)&arow[4];
    ta2 = *(const float4*)&arow[8];  ta3 = *(const float4*)&arow[12];
    for (int ch = tid; ch < 1536; ch += 256)
        GLDS16((const char*)wcat + ch * 16, (char*)Bsm[0] + ch * 16);
    {
        uint4 v0 = make_uint4(cvtpk(ta0.x, ta0.y), cvtpk(ta0.z, ta0.w),
                              cvtpk(ta1.x, ta1.y), cvtpk(ta1.z, ta1.w));
        uint4 v1 = make_uint4(cvtpk(ta2.x, ta2.y), cvtpk(ta2.z, ta2.w),
                              cvtpk(ta3.x, ta3.y), cvtpk(ta3.z, ta3.w));
        *(uint4*)((char*)Asm[0] + ((sq * 2) * 32 + sm) * 16) = v0;
        *(uint4*)((char*)Asm[0] + ((sq * 2 + 1) * 32 + sm) * 16) = v1;
    }
    __syncthreads();

    int cur = 0;
    for (int s = 0; s < 6; ++s) {
        if (s < 5) {
            const float* src = arow + (s + 1) * 128;
            ta0 = *(const float4*)&src[0];  ta1 = *(const float4*)&src[4];
            ta2 = *(const float4*)&src[8];  ta3 = *(const float4*)&src[12];
            // B K-range for step s+1 is contiguous: 16 kg x 96 c x 8 shorts
            const char* bsrc = (const char*)wcat + (size_t)(s + 1) * 24576;
            for (int ch = tid; ch < 1536; ch += 256)
                GLDS16(bsrc + ch * 16, (char*)Bsm[cur ^ 1] + ch * 16);
        }
        const bf16x8* Ap = (const bf16x8*)Asm[cur];
        const bf16x8* Bp = (const bf16x8*)Bsm[cur];
        #pragma unroll
        for (int ks = 0; ks < 4; ++ks) {
            int kg = lq + ks * 4;   // 0..15
            bf16x8 av = Ap[kg * 32 + wm * 16 + l15];
            bf16x8 bv[3];
            #pragma unroll
            for (int j = 0; j < 3; ++j)
                bv[j] = Bp[kg * 96 + wn * 48 + j * 16 + l15];
            #pragma unroll
            for (int j = 0; j < 3; ++j)
                acc[j] = __builtin_amdgcn_mfma_f32_16x16x32_bf16(
                    av, bv[j], acc[j], 0, 0, 0);
        }
        if (s < 5) {
            uint4 v0 = make_uint4(cvtpk(ta0.x, ta0.y), cvtpk(ta0.z, ta0.w),
                                  cvtpk(ta1.x, ta1.y), cvtpk(ta1.z, ta1.w));
            uint4 v1 = make_uint4(cvtpk(ta2.x, ta2.y), cvtpk(ta2.z, ta2.w),
                                  cvtpk(ta3.x, ta3.y), cvtpk(ta3.z, ta3.w));
            *(uint4*)((char*)Asm[cur ^ 1] + ((sq * 2) * 32 + sm) * 16) = v0;
            *(uint4*)((char*)Asm[cur ^ 1] + ((sq * 2 + 1) * 32 + sm) * 16) = v1;
        }
        __syncthreads();
        cur ^= 1;
    }

    // epilogue: stage bf16 into LDS (reuse Asm), then 16B coalesced stores
    ushort* fs = (ushort*)Asm[0];   // 32 x 64
    ushort* ys = (ushort*)Asm[1];   // 32 x 32
    float bb[3];
    #pragma unroll
    for (int j = 0; j < 3; ++j) bb[j] = bcat[wn * 48 + j * 16 + l15];
    #pragma unroll
    for (int j = 0; j < 3; ++j) {
        int c = wn * 48 + j * 16 + l15;
        int mlb = wm * 16 + (lq << 2);
        #pragma unroll
        for (int r = 0; r < 4; ++r) {
            float v = acc[j][r] + bb[j];
            if (c < 64) fs[(mlb + r) * 64 + c] = f2bf(v);
            else        ys[(mlb + r) * 32 + (c - 64)] = f2bf(fmaxf(v, 0.0f));
        }
    }
    __syncthreads();
    {
        int ml = tid >> 3, cq = (tid & 7) * 8;
        *(uint4*)&featb[(size_t)(row0 + ml) * CF + cq] = *(const uint4*)&fs[ml * 64 + cq];
    }
    if (tid < 128) {
        int ml = tid >> 2, cq = (tid & 3) * 8;
        *(uint4*)&ybb[(size_t)(row0 + ml) * CHH + cq] = *(const uint4*)&ys[ml * 32 + cq];
    }
}

// ---------------------------------------------------------------------------
// K23: fused HT (CSR gather from bf16 y, 16B loads) + (9,1) rho-conv via MFMA.
__global__ __launch_bounds__(256) void k23_ht_conv(
    const ushort* __restrict__ ybb, const int* __restrict__ perm,
    const int* __restrict__ rowptr, const short* __restrict__ w2t,
    ushort* __restrict__ htcT) {
    __shared__ int pperm[NTOK];                      // 4 KB
    __shared__ int prow[90];
    __shared__ __align__(16) short insp[104 * 40];   // 8.3 KB bf16, stride 40
    __shared__ uint outtu[NRHO * 18];                // 6.4 KB packed bf16 pairs

    const int tid = threadIdx.x;
    const int lane = tid & 63, wave = tid >> 6;
    const int wm = wave >> 1, wn = wave & 1;
    const int b = blockIdx.x / NTH, t = blockIdx.x % NTH;

    bf16x8 av[9];
    #pragma unroll
    for (int k = 0; k < 9; ++k)
        av[k] = *(const bf16x8*)&w2t[(((k * 2 + wm) * 64) + lane) * 8];

    for (int i = tid; i < NTOK; i += 256) pperm[i] = perm[t * NTOK + i];
    for (int i = tid; i < 90; i += 256) prow[i] = rowptr[t * 90 + i];
    for (int i = tid; i < 104 * 40 / 2; i += 256) ((uint*)insp)[i] = 0;
    __syncthreads();

    {   // 4 channel-groups x 64 rho-groups; 16B y loads
        const int c0 = (tid & 3) * 8, g = tid >> 2;
        const ushort* yp = ybb + (size_t)b * NTOK * CHH + c0;
        for (int rho = g; rho < NRHO; rho += 64) {
            int p0 = prow[rho], p1 = prow[rho + 1];
            float s0 = 0, s1 = 0, s2 = 0, s3 = 0, s4 = 0, s5 = 0, s6 = 0, s7 = 0;
            for (int k = p0; k < p1; ++k) {
                int n = pperm[k];
                uint4 v = *(const uint4*)&yp[n * CHH];
                s0 += bf2f((ushort)(v.x & 0xffff)); s1 += bf2f((ushort)(v.x >> 16));
                s2 += bf2f((ushort)(v.y & 0xffff)); s3 += bf2f((ushort)(v.y >> 16));
                s4 += bf2f((ushort)(v.z & 0xffff)); s5 += bf2f((ushort)(v.z >> 16));
                s6 += bf2f((ushort)(v.w & 0xffff)); s7 += bf2f((ushort)(v.w >> 16));
            }
            float iv = 1.0f / fmaxf((float)(p1 - p0), 1.0f);
            uint4 pk = make_uint4(cvtpk(s0 * iv, s1 * iv), cvtpk(s2 * iv, s3 * iv),
                                  cvtpk(s4 * iv, s5 * iv), cvtpk(s6 * iv, s7 * iv));
            *(uint4*)&insp[(rho + 4) * 40 + c0] = pk;
        }
    }
    __syncthreads();

    f32x4 acc[3] = {};
    #pragma unroll
    for (int f = 0; f < 3; ++f) {
        int Rn = wn * 48 + f * 16 + (lane & 15);
        #pragma unroll
        for (int k = 0; k < 9; ++k) {
            bf16x8 bv = *(const bf16x8*)&insp[(Rn + k) * 40 + ((lane >> 4) << 3)];
            acc[f] = __builtin_amdgcn_mfma_f32_16x16x32_bf16(av[k], bv, acc[f], 0, 0, 0);
        }
    }
    #pragma unroll
    for (int f = 0; f < 3; ++f) {
        int r = wn * 48 + f * 16 + (lane & 15);
        if (r < NRHO) {
            int ob = wm * 8 + ((lane >> 4) << 1);
            outtu[r * 18 + ob]     = cvtpk(fmaxf(acc[f][0], 0.0f), fmaxf(acc[f][1], 0.0f));
            outtu[r * 18 + ob + 1] = cvtpk(fmaxf(acc[f][2], 0.0f), fmaxf(acc[f][3], 0.0f));
        }
    }
    __syncthreads();

    {
        ushort* dst = htcT + (size_t)(b * NTH + t) * (NRHO * CHH);
        for (int idx = tid; idx < NRHO * 8; idx += 256) {
            int r = idx >> 3, q = idx & 7;
            uint2 v;
            v.x = outtu[r * 18 + q * 2];
            v.y = outtu[r * 18 + q * 2 + 1];
            *(uint2*)&dst[r * CHH + q * 4] = v;
        }
    }
}

// ---------------------------------------------------------------------------
// K45 (barrier-free version): iht gather -> z-GEMM -> A (LDS) -> out GEMM
// with A frags hoisted to regs and B frags direct from L2-hot wout.
// 512 blocks x 256 thr, 64-token tiles, 20 KB LDS.
__global__ __launch_bounds__(256, 4) void k45_iht_out(
    const ushort* __restrict__ htcT, const uchar* __restrict__ rho8,
    const float* __restrict__ W3, const ushort* __restrict__ featb,
    const short* __restrict__ wout, const float* __restrict__ bt_out,
    float* __restrict__ out) {
    __shared__ float w3t[32 * 64];                 // 8 KB
    __shared__ uchar lrho[NTH * 64];               // 3.75 KB
    __shared__ float ihts[64 * 32];                // 8 KB
    __shared__ __align__(16) short Alds[4096];     // 8 KB [kg8][m64][k8]

    const int tid = threadIdx.x;
    const int lane = tid & 63, wave = tid >> 6;
    const int wm = wave >> 1, wn = wave & 1;
    const int bid = blockIdx.x;
    const int b = bid >> 4;
    const int n0 = (bid & 15) * 64;
    const int l15 = lane & 15, lq = lane >> 4;

    // phase 1a: scratch loads
    for (int idx = tid; idx < 2048; idx += 256) {
        int c = idx >> 6, j = idx & 63;
        w3t[idx] = W3[j * 32 + c];
    }
    for (int idx = tid; idx < NTH * 64; idx += 256)
        lrho[idx] = rho8[(idx >> 6) * NTOK + n0 + (idx & 63)];
    __syncthreads();

    // phase 1b: iht gather, 1 token x 8 channels per thread (16B loads)
    {
        const int c0 = (tid & 3) * 8, tok = tid >> 2;
        const ushort* hb = htcT + (size_t)b * NTH * NRHO * CHH + c0;
        float s[8] = {};
        #pragma unroll 6
        for (int t = 0; t < NTH; ++t) {
            int r = lrho[t * 64 + tok];
            uint4 v = *(const uint4*)&hb[(size_t)(t * NRHO + r) * CHH];
            s[0] += bf2f((ushort)(v.x & 0xffff)); s[1] += bf2f((ushort)(v.x >> 16));
            s[2] += bf2f((ushort)(v.y & 0xffff)); s[3] += bf2f((ushort)(v.y >> 16));
            s[4] += bf2f((ushort)(v.z & 0xffff)); s[5] += bf2f((ushort)(v.z >> 16));
            s[6] += bf2f((ushort)(v.w & 0xffff)); s[7] += bf2f((ushort)(v.w >> 16));
        }
        float4 r0, r1;
        r0.x = s[0] * (1.0f / 60.0f); r0.y = s[1] * (1.0f / 60.0f);
        r0.z = s[2] * (1.0f / 60.0f); r0.w = s[3] * (1.0f / 60.0f);
        r1.x = s[4] * (1.0f / 60.0f); r1.y = s[5] * (1.0f / 60.0f);
        r1.z = s[6] * (1.0f / 60.0f); r1.w = s[7] * (1.0f / 60.0f);
        *(float4*)&ihts[tok * 32 + c0] = r0;
        *(float4*)&ihts[tok * 32 + c0 + 4] = r1;
    }
    __syncthreads();

    // phase 1c: z = iht @ W3^T; A = bf16(feat + z) packed [kg8][m64][k8]
    {
        const int j = tid & 63, nb = tid >> 6;
        ushort* Au = (ushort*)Alds;
        for (int nn = nb; nn < 64; nn += 4) {
            float z = 0.0f;
            #pragma unroll 8
            for (int cc = 0; cc < 32; ++cc) z += ihts[nn * 32 + cc] * w3t[cc * 64 + j];
            float v = bf2f(featb[(size_t)(bid * 64 + nn) * CF + j]) + z;
            Au[((j >> 3) * 64 + nn) * 8 + (j & 7)] = f2bf(v);
        }
    }
    __syncthreads();

    // phase 2: hoist A frags to regs (db-invariant), then barrier-free db loop
    const bf16x8* Ap = (const bf16x8*)Alds;
    bf16x8 avr[2][2];   // [ks][i]
    #pragma unroll
    for (int ks = 0; ks < 2; ++ks) {
        int kg = lq + ks * 4;
        #pragma unroll
        for (int i = 0; i < 2; ++i)
            avr[ks][i] = Ap[kg * 64 + wm * 32 + i * 16 + l15];
    }

    const short* bbase = wout + ((size_t)lq * 128 + wn * 64 + l15) * 8;
    for (int db = 0; db < 6; ++db) {
        f32x4 acc[2][4] = {};
        #pragma unroll
        for (int ks = 0; ks < 2; ++ks) {
            const short* bp = bbase + ((size_t)(db * 8 + ks * 4) * 128) * 8;
            bf16x8 bvv[4];
            #pragma unroll
            for (int jf = 0; jf < 4; ++jf)
                bvv[jf] = *(const bf16x8*)&bp[jf * 16 * 8];
            #pragma unroll
            for (int i = 0; i < 2; ++i)
                #pragma unroll
                for (int jf = 0; jf < 4; ++jf)
                    acc[i][jf] = __builtin_amdgcn_mfma_f32_16x16x32_bf16(
                        avr[ks][i], bvv[jf], acc[i][jf], 0, 0, 0);
        }
        const int d0 = db * 128 + wn * 64 + l15;
        float bb[4];
        #pragma unroll
        for (int jf = 0; jf < 4; ++jf) bb[jf] = bt_out[d0 + jf * 16];
        const int mrow = bid * 64 + wm * 32 + (lq << 2);
        #pragma unroll
        for (int i = 0; i < 2; ++i)
            #pragma unroll
            for (int r = 0; r < 4; ++r)
                #pragma unroll
                for (int jf = 0; jf < 4; ++jf)
                    out[(size_t)(mrow + i * 16 + r) * DMODEL + d0 + jf * 16] =
                        acc[i][jf][r] + bb[jf];
    }
}

// ---------------------------------------------------------------------------
extern "C" void kernel_launch(void* const* d_in, const int* in_sizes, int n_in,
                              void* d_out, int out_size, void* d_ws, size_t ws_size,
                              hipStream_t stream) {
    const float* tokens = (const float*)d_in[0];
    const float* Wt_in  = (const float*)d_in[2];
    const float* bt_in  = (const float*)d_in[3];
    const float* W1     = (const float*)d_in[4];
    const float* W2     = (const float*)d_in[5];
    const float* W3     = (const float*)d_in[6];
    const float* Wt_out = (const float*)d_in[7];
    const float* bt_out = (const float*)d_in[8];
    float* out = (float*)d_out;

    // workspace layout (bytes, 16-aligned)
    char* w = (char*)d_ws;
    int*    perm   = (int*)(w);                  // 245760   -> 245760
    int*    rowptr = (int*)(w + 245760);         // 21600    -> 267360
    uchar*  rho8   = (uchar*)(w + 267360);       // 61440    -> 328800
    short*  wcat   = (short*)(w + 328800);       // 147456   -> 476256
    float*  bcat   = (float*)(w + 476256);       // 384      -> 476640
    short*  wout   = (short*)(w + 476640);       // 98304    -> 574944
    short*  w2t    = (short*)(w + 574944);       // 18432    -> 593376
    ushort* featb  = (ushort*)(w + 593376);      // 4194304  -> 4787680
    ushort* ybb    = (ushort*)(w + 4787680);     // 2097152  -> 6884832
    ushort* htcT   = (ushort*)(w + 6884832);     // 10936320 -> 17821152

    k0_prep<<<216, 256, 0, stream>>>(perm, rowptr, rho8, Wt_in, bt_in, W1,
                                     wcat, bcat, Wt_out, W2, wout, w2t);
    k1_mfma<<<NB * NTOK / 32, 256, 0, stream>>>(tokens, wcat, bcat, featb, ybb);
    k23_ht_conv<<<NB * NTH, 256, 0, stream>>>(ybb, perm, rowptr, w2t, htcT);
    k45_iht_out<<<NB * (NTOK / 64), 256, 0, stream>>>(htcT, rho8, W3, featb,
                                                      wout, bt_out, out);
}

// Round 20
// 99.127 us; speedup vs baseline: 1.0594x; 1.0594x over previous
//
#include <hip/hip_runtime.h>
#include <math.h>

// Problem constants (fixed by reference: B=32, 32x32 tokens, DM=768, C=64, ch=32,
// theta_res=3 -> 60 thetas, rho_res=1 on 32x32 -> q=44 -> 89 rhos)
#define NB    32
#define NTOK  1024
#define DMODEL 768
#define CF    64
#define CHH   32
#define NRHO  89
#define NTH   60
#define HRB   (NRHO*NTH)  // 5340

typedef short bf16x8 __attribute__((ext_vector_type(8)));
typedef float f32x4  __attribute__((ext_vector_type(4)));
typedef unsigned int uint;
typedef unsigned short ushort;
typedef unsigned char uchar;

__device__ __forceinline__ ushort f2bf(float f) {
    uint u = __float_as_uint(f);
    return (ushort)((u + 0x7FFF + ((u >> 16) & 1)) >> 16);
}
__device__ __forceinline__ float bf2f(ushort u) {
    return __uint_as_float(((uint)u) << 16);
}
// HW packed convert: dst[15:0]=bf16(lo), dst[31:16]=bf16(hi). RTNE, same as f2bf.
__device__ __forceinline__ uint cvtpk(float lo, float hi) {
    uint r;
    asm("v_cvt_pk_bf16_f32 %0, %1, %2" : "=v"(r) : "v"(lo), "v"(hi));
    return r;
}

#define GLDS16(gp, lp) __builtin_amdgcn_global_load_lds( \
    (const __attribute__((address_space(1))) unsigned int*)(gp), \
    (__attribute__((address_space(3))) unsigned int*)(lp), 16, 0, 0)

// ---------------------------------------------------------------------------
// K0 mega-kernel:
//  blocks 0..59    : per-theta CSR (counting sort) + rho8[t][n] byte table
//  blocks 60..155  : Wcat = [Wt_in; W1@Wt_in] -> bf16 tiled, bcat
//  blocks 156..215 : Wt_out -> wout tiled; W2 -> w2t MFMA A-frags
__global__ __launch_bounds__(256) void k0_prep(
    int* __restrict__ perm, int* __restrict__ rowptr, uchar* __restrict__ rho8,
    const float* __restrict__ Wt_in, const float* __restrict__ bt_in,
    const float* __restrict__ W1, short* __restrict__ wcat,
    float* __restrict__ bcat,
    const float* __restrict__ Wt_out, const float* __restrict__ W2,
    short* __restrict__ wout, short* __restrict__ w2t) {
    __shared__ int rho_n[NTOK];
    __shared__ int cnt2[64 * 90];
    __shared__ int tot[96];
    __shared__ int base[96];
    __shared__ float w1row[64];
    const int tid = threadIdx.x;
    const int blk = blockIdx.x;

    if (blk < 60) {
        const int t = blk;
        const double rad = ((double)(t * 3)) * (M_PI / 180.0);
        const double ct = cos(rad), st = sin(rad);
        for (int n = tid; n < NTOK; n += 256) {
            int i = n >> 5, j = n & 31;
            double rho = (double)(j - 16) * ct + (double)(16 - i) * st;
            int ridx = (int)rint(rho) + 44;
            rho_n[n] = ridx;
            rho8[t * NTOK + n] = (uchar)ridx;
        }
        for (int i = tid; i < 64 * 90; i += 256) cnt2[i] = 0;
        __syncthreads();
        for (int n = tid; n < NTOK; n += 256)
            atomicAdd(&cnt2[(n >> 4) * 90 + rho_n[n]], 1);
        __syncthreads();
        if (tid < NRHO) {
            int s = 0;
            for (int c = 0; c < 64; ++c) {
                int v = cnt2[c * 90 + tid];
                cnt2[c * 90 + tid] = s;
                s += v;
            }
            tot[tid] = s;
        }
        __syncthreads();
        if (tid == 0) {
            int s = 0;
            for (int r = 0; r < NRHO; ++r) { base[r] = s; s += tot[r]; }
            base[NRHO] = s;
        }
        __syncthreads();
        if (tid < NRHO + 1) rowptr[t * 90 + tid] = base[tid];
        if (tid < 64) {
            const int c = tid;
            #pragma unroll
            for (int j = 0; j < 16; ++j) {
                int n = c * 16 + j;
                int r = rho_n[n];
                int cur = cnt2[c * 90 + r];
                cnt2[c * 90 + r] = cur + 1;
                perm[t * NTOK + base[r] + cur] = n;
            }
        }
    } else if (blk < 156) {
        const int c = blk - 60;   // 0..95
        if (c >= 64)
            for (int j = tid; j < 64; j += 256) w1row[j] = W1[(c - 64) * 64 + j];
        __syncthreads();
        for (int k = tid; k < DMODEL; k += 256) {
            float v;
            if (c < 64) v = Wt_in[c * DMODEL + k];
            else {
                v = 0.0f;
                for (int j = 0; j < 64; ++j) v += w1row[j] * Wt_in[j * DMODEL + k];
            }
            int kt = k >> 6, kk = k & 63;
            wcat[(((kt << 3) + (kk >> 3)) * 96 + c) * 8 + (k & 7)] = (short)f2bf(v);
        }
        if (tid == 0) {
            float bv;
            if (c < 64) bv = bt_in[c];
            else {
                bv = 0.0f;
                for (int j = 0; j < 64; ++j) bv += W1[(c - 64) * 64 + j] * bt_in[j];
            }
            bcat[c] = bv;
        }
    } else {
        int idx = (blk - 156) * 256 + tid;   // 15360 total
        if (idx < 6144) {
            int d = idx >> 3, kg = idx & 7;
            float4 a = *(const float4*)&Wt_out[d * 64 + kg * 8];
            float4 b = *(const float4*)&Wt_out[d * 64 + kg * 8 + 4];
            uint4 v = make_uint4(cvtpk(a.x, a.y), cvtpk(a.z, a.w),
                                 cvtpk(b.x, b.y), cvtpk(b.z, b.w));
            *(uint4*)&wout[(((d >> 7) * 8 + kg) * 128 + (d & 127)) * 8] = v;
        } else if (idx < 6144 + 9216) {
            int q = idx - 6144;
            int e = q & 7, ln = (q >> 3) & 63, wm = (q >> 9) & 1, k = q >> 10;
            int o = wm * 16 + (ln & 15), i = ((ln >> 4) << 3) + e;
            w2t[q] = (short)f2bf(W2[(o * 32 + i) * 9 + k]);
        }
    }
}

// ---------------------------------------------------------------------------
// K1 v8 (best known): GLDS-staged MFMA GEMM at full occupancy: 512-thread
// blocks (8 waves), 64-row tiles, grid 512, LDS 40 KB -> 4 blocks/CU = 32
// waves/CU. [feat|y] = tokens @ Wcat^T + bcat. A via regs+cvtpk; B via GLDS
// dwordx4, double-buffered.
__global__ __launch_bounds__(512, 8) void k1_mfma(
    const float* __restrict__ tokens, const short* __restrict__ wcat,
    const float* __restrict__ bcat, ushort* __restrict__ featb,
    ushort* __restrict__ ybb) {
    __shared__ __align__(16) short Asm[2][4096];   // [kg8][m64][k8], 8 KB each
    __shared__ __align__(16) short Bsm[2][6144];   // [kg8][c96][k8], 12 KB each

    const int tid = threadIdx.x;
    const int lane = tid & 63, wave = tid >> 6;    // 8 waves
    const int wm = wave >> 1, wn = wave & 1;       // wm 0..3 (16 rows), wn 0..1
    const int row0 = blockIdx.x * 64;
    const int l15 = lane & 15, lq = lane >> 4;
    const int sm = tid >> 3, sq = tid & 7;         // staging: 64 rows x 8 kgroups

    const float* arow = tokens + (size_t)(row0 + sm) * DMODEL + sq * 8;

    f32x4 acc[3] = {};
    float4 ta0, ta1;

    // prologue: stage kt=0
    ta0 = *(const float4*)&arow[0];
    ta1 = *(const float4*)&arow[4];
    for (int ch = tid; ch < 768; ch += 512)
        GLDS16((const char*)wcat + ch * 16, (char*)Bsm[0] + ch * 16);
    {
        uint4 v = make_uint4(cvtpk(ta0.x, ta0.y), cvtpk(ta0.z, ta0.w),
                             cvtpk(ta1.x, ta1.y), cvtpk(ta1.z, ta1.w));
        *(uint4*)((char*)Asm[0] + (sq * 64 + sm) * 16) = v;
    }
    __syncthreads();

    int cur = 0;
    for (int kt = 0; kt < 12; ++kt) {
        if (kt < 11) {
            const float* src = arow + (kt + 1) * 64;
            ta0 = *(const float4*)&src[0];
            ta1 = *(const float4*)&src[4];
            const char* bsrc = (const char*)wcat + (size_t)(kt + 1) * 12288;
            for (int ch = tid; ch < 768; ch += 512)
                GLDS16(bsrc + ch * 16, (char*)Bsm[cur ^ 1] + ch * 16);
        }
        const bf16x8* Ap = (const bf16x8*)Asm[cur];
        const bf16x8* Bp = (const bf16x8*)Bsm[cur];
        #pragma unroll
        for (int ks = 0; ks < 2; ++ks) {
            int kg = lq + ks * 4;
            bf16x8 av = Ap[kg * 64 + wm * 16 + l15];
            bf16x8 bv[3];
            #pragma unroll
            for (int j = 0; j < 3; ++j)
                bv[j] = Bp[kg * 96 + wn * 48 + j * 16 + l15];
            #pragma unroll
            for (int j = 0; j < 3; ++j)
                acc[j] = __builtin_amdgcn_mfma_f32_16x16x32_bf16(
                    av, bv[j], acc[j], 0, 0, 0);
        }
        if (kt < 11) {
            uint4 v = make_uint4(cvtpk(ta0.x, ta0.y), cvtpk(ta0.z, ta0.w),
                                 cvtpk(ta1.x, ta1.y), cvtpk(ta1.z, ta1.w));
            *(uint4*)((char*)Asm[cur ^ 1] + (sq * 64 + sm) * 16) = v;
        }
        __syncthreads();
        cur ^= 1;
    }

    // epilogue: stage bf16 into LDS (reuse Asm), then 16B coalesced stores
    ushort* fs = (ushort*)Asm[0];   // 64 x 64 (8 KB)
    ushort* ys = (ushort*)Asm[1];   // 64 x 32 (4 KB)
    float bb[3];
    #pragma unroll
    for (int j = 0; j < 3; ++j) bb[j] = bcat[wn * 48 + j * 16 + l15];
    #pragma unroll
    for (int j = 0; j < 3; ++j) {
        int c = wn * 48 + j * 16 + l15;
        int mlb = wm * 16 + (lq << 2);
        #pragma unroll
        for (int r = 0; r < 4; ++r) {
            float v = acc[j][r] + bb[j];
            if (c < 64) fs[(mlb + r) * 64 + c] = f2bf(v);
            else        ys[(mlb + r) * 32 + (c - 64)] = f2bf(fmaxf(v, 0.0f));
        }
    }
    __syncthreads();
    {
        int ml = tid >> 3, cq = (tid & 7) * 8;   // 512 chunks
        *(uint4*)&featb[(size_t)(row0 + ml) * CF + cq] = *(const uint4*)&fs[ml * 64 + cq];
    }
    if (tid < 256) {
        int ml = tid >> 2, cq = (tid & 3) * 8;   // 256 chunks
        *(uint4*)&ybb[(size_t)(row0 + ml) * CHH + cq] = *(const uint4*)&ys[ml * 32 + cq];
    }
}

// ---------------------------------------------------------------------------
// K23: fused HT (CSR gather from bf16 y, 16B loads) + (9,1) rho-conv via MFMA.
__global__ __launch_bounds__(256) void k23_ht_conv(
    const ushort* __restrict__ ybb, const int* __restrict__ perm,
    const int* __restrict__ rowptr, const short* __restrict__ w2t,
    ushort* __restrict__ htcT) {
    __shared__ int pperm[NTOK];                      // 4 KB
    __shared__ int prow[90];
    __shared__ __align__(16) short insp[104 * 40];   // 8.3 KB bf16, stride 40
    __shared__ uint outtu[NRHO * 18];                // 6.4 KB packed bf16 pairs

    const int tid = threadIdx.x;
    const int lane = tid & 63, wave = tid >> 6;
    const int wm = wave >> 1, wn = wave & 1;
    const int b = blockIdx.x / NTH, t = blockIdx.x % NTH;

    bf16x8 av[9];
    #pragma unroll
    for (int k = 0; k < 9; ++k)
        av[k] = *(const bf16x8*)&w2t[(((k * 2 + wm) * 64) + lane) * 8];

    for (int i = tid; i < NTOK; i += 256) pperm[i] = perm[t * NTOK + i];
    for (int i = tid; i < 90; i += 256) prow[i] = rowptr[t * 90 + i];
    for (int i = tid; i < 104 * 40 / 2; i += 256) ((uint*)insp)[i] = 0;
    __syncthreads();

    {   // 4 channel-groups x 64 rho-groups; 16B y loads
        const int c0 = (tid & 3) * 8, g = tid >> 2;
        const ushort* yp = ybb + (size_t)b * NTOK * CHH + c0;
        for (int rho = g; rho < NRHO; rho += 64) {
            int p0 = prow[rho], p1 = prow[rho + 1];
            float s0 = 0, s1 = 0, s2 = 0, s3 = 0, s4 = 0, s5 = 0, s6 = 0, s7 = 0;
            for (int k = p0; k < p1; ++k) {
                int n = pperm[k];
                uint4 v = *(const uint4*)&yp[n * CHH];
                s0 += bf2f((ushort)(v.x & 0xffff)); s1 += bf2f((ushort)(v.x >> 16));
                s2 += bf2f((ushort)(v.y & 0xffff)); s3 += bf2f((ushort)(v.y >> 16));
                s4 += bf2f((ushort)(v.z & 0xffff)); s5 += bf2f((ushort)(v.z >> 16));
                s6 += bf2f((ushort)(v.w & 0xffff)); s7 += bf2f((ushort)(v.w >> 16));
            }
            float iv = 1.0f / fmaxf((float)(p1 - p0), 1.0f);
            uint4 pk = make_uint4(cvtpk(s0 * iv, s1 * iv), cvtpk(s2 * iv, s3 * iv),
                                  cvtpk(s4 * iv, s5 * iv), cvtpk(s6 * iv, s7 * iv));
            *(uint4*)&insp[(rho + 4) * 40 + c0] = pk;
        }
    }
    __syncthreads();

    f32x4 acc[3] = {};
    #pragma unroll
    for (int f = 0; f < 3; ++f) {
        int Rn = wn * 48 + f * 16 + (lane & 15);
        #pragma unroll
        for (int k = 0; k < 9; ++k) {
            bf16x8 bv = *(const bf16x8*)&insp[(Rn + k) * 40 + ((lane >> 4) << 3)];
            acc[f] = __builtin_amdgcn_mfma_f32_16x16x32_bf16(av[k], bv, acc[f], 0, 0, 0);
        }
    }
    #pragma unroll
    for (int f = 0; f < 3; ++f) {
        int r = wn * 48 + f * 16 + (lane & 15);
        if (r < NRHO) {
            int ob = wm * 8 + ((lane >> 4) << 1);
            outtu[r * 18 + ob]     = cvtpk(fmaxf(acc[f][0], 0.0f), fmaxf(acc[f][1], 0.0f));
            outtu[r * 18 + ob + 1] = cvtpk(fmaxf(acc[f][2], 0.0f), fmaxf(acc[f][3], 0.0f));
        }
    }
    __syncthreads();

    {
        ushort* dst = htcT + (size_t)(b * NTH + t) * (NRHO * CHH);
        for (int idx = tid; idx < NRHO * 8; idx += 256) {
            int r = idx >> 3, q = idx & 7;
            uint2 v;
            v.x = outtu[r * 18 + q * 2];
            v.y = outtu[r * 18 + q * 2 + 1];
            *(uint2*)&dst[r * CHH + q * 4] = v;
        }
    }
}

// ---------------------------------------------------------------------------
// K45 (barrier-free): iht gather -> z-GEMM -> A (LDS) -> out GEMM with A
// frags hoisted to regs and B frags direct from L2-hot wout. 512 blocks x
// 256 thr, 64-token tiles, 20 KB LDS.
__global__ __launch_bounds__(256, 4) void k45_iht_out(
    const ushort* __restrict__ htcT, const uchar* __restrict__ rho8,
    const float* __restrict__ W3, const ushort* __restrict__ featb,
    const short* __restrict__ wout, const float* __restrict__ bt_out,
    float* __restrict__ out) {
    __shared__ float w3t[32 * 64];                 // 8 KB
    __shared__ uchar lrho[NTH * 64];               // 3.75 KB
    __shared__ float ihts[64 * 32];                // 8 KB
    __shared__ __align__(16) short Alds[4096];     // 8 KB [kg8][m64][k8]

    const int tid = threadIdx.x;
    const int lane = tid & 63, wave = tid >> 6;
    const int wm = wave >> 1, wn = wave & 1;
    const int bid = blockIdx.x;
    const int b = bid >> 4;
    const int n0 = (bid & 15) * 64;
    const int l15 = lane & 15, lq = lane >> 4;

    // phase 1a: scratch loads
    for (int idx = tid; idx < 2048; idx += 256) {
        int c = idx >> 6, j = idx & 63;
        w3t[idx] = W3[j * 32 + c];
    }
    for (int idx = tid; idx < NTH * 64; idx += 256)
        lrho[idx] = rho8[(idx >> 6) * NTOK + n0 + (idx & 63)];
    __syncthreads();

    // phase 1b: iht gather, 1 token x 8 channels per thread (16B loads)
    {
        const int c0 = (tid & 3) * 8, tok = tid >> 2;
        const ushort* hb = htcT + (size_t)b * NTH * NRHO * CHH + c0;
        float s[8] = {};
        #pragma unroll 6
        for (int t = 0; t < NTH; ++t) {
            int r = lrho[t * 64 + tok];
            uint4 v = *(const uint4*)&hb[(size_t)(t * NRHO + r) * CHH];
            s[0] += bf2f((ushort)(v.x & 0xffff)); s[1] += bf2f((ushort)(v.x >> 16));
            s[2] += bf2f((ushort)(v.y & 0xffff)); s[3] += bf2f((ushort)(v.y >> 16));
            s[4] += bf2f((ushort)(v.z & 0xffff)); s[5] += bf2f((ushort)(v.z >> 16));
            s[6] += bf2f((ushort)(v.w & 0xffff)); s[7] += bf2f((ushort)(v.w >> 16));
        }
        float4 r0, r1;
        r0.x = s[0] * (1.0f / 60.0f); r0.y = s[1] * (1.0f / 60.0f);
        r0.z = s[2] * (1.0f / 60.0f); r0.w = s[3] * (1.0f / 60.0f);
        r1.x = s[4] * (1.0f / 60.0f); r1.y = s[5] * (1.0f / 60.0f);
        r1.z = s[6] * (1.0f / 60.0f); r1.w = s[7] * (1.0f / 60.0f);
        *(float4*)&ihts[tok * 32 + c0] = r0;
        *(float4*)&ihts[tok * 32 + c0 + 4] = r1;
    }
    __syncthreads();

    // phase 1c: z = iht @ W3^T; A = bf16(feat + z) packed [kg8][m64][k8]
    {
        const int j = tid & 63, nb = tid >> 6;
        ushort* Au = (ushort*)Alds;
        for (int nn = nb; nn < 64; nn += 4) {
            float z = 0.0f;
            #pragma unroll 8
            for (int cc = 0; cc < 32; ++cc) z += ihts[nn * 32 + cc] * w3t[cc * 64 + j];
            float v = bf2f(featb[(size_t)(bid * 64 + nn) * CF + j]) + z;
            Au[((j >> 3) * 64 + nn) * 8 + (j & 7)] = f2bf(v);
        }
    }
    __syncthreads();

    // phase 2: hoist A frags to regs (db-invariant), then barrier-free db loop
    const bf16x8* Ap = (const bf16x8*)Alds;
    bf16x8 avr[2][2];   // [ks][i]
    #pragma unroll
    for (int ks = 0; ks < 2; ++ks) {
        int kg = lq + ks * 4;
        #pragma unroll
        for (int i = 0; i < 2; ++i)
            avr[ks][i] = Ap[kg * 64 + wm * 32 + i * 16 + l15];
    }

    const short* bbase = wout + ((size_t)lq * 128 + wn * 64 + l15) * 8;
    for (int db = 0; db < 6; ++db) {
        f32x4 acc[2][4] = {};
        #pragma unroll
        for (int ks = 0; ks < 2; ++ks) {
            const short* bp = bbase + ((size_t)(db * 8 + ks * 4) * 128) * 8;
            bf16x8 bvv[4];
            #pragma unroll
            for (int jf = 0; jf < 4; ++jf)
                bvv[jf] = *(const bf16x8*)&bp[jf * 16 * 8];
            #pragma unroll
            for (int i = 0; i < 2; ++i)
                #pragma unroll
                for (int jf = 0; jf < 4; ++jf)
                    acc[i][jf] = __builtin_amdgcn_mfma_f32_16x16x32_bf16(
                        avr[ks][i], bvv[jf], acc[i][jf], 0, 0, 0);
        }
        const int d0 = db * 128 + wn * 64 + l15;
        float bb[4];
        #pragma unroll
        for (int jf = 0; jf < 4; ++jf) bb[jf] = bt_out[d0 + jf * 16];
        const int mrow = bid * 64 + wm * 32 + (lq << 2);
        #pragma unroll
        for (int i = 0; i < 2; ++i)
            #pragma unroll
            for (int r = 0; r < 4; ++r)
                #pragma unroll
                for (int jf = 0; jf < 4; ++jf)
                    out[(size_t)(mrow + i * 16 + r) * DMODEL + d0 + jf * 16] =
                        acc[i][jf][r] + bb[jf];
    }
}

// ---------------------------------------------------------------------------
extern "C" void kernel_launch(void* const* d_in, const int* in_sizes, int n_in,
                              void* d_out, int out_size, void* d_ws, size_t ws_size,
                              hipStream_t stream) {
    const float* tokens = (const float*)d_in[0];
    const float* Wt_in  = (const float*)d_in[2];
    const float* bt_in  = (const float*)d_in[3];
    const float* W1     = (const float*)d_in[4];
    const float* W2     = (const float*)d_in[5];
    const float* W3     = (const float*)d_in[6];
    const float* Wt_out = (const float*)d_in[7];
    const float* bt_out = (const float*)d_in[8];
    float* out = (float*)d_out;

    // workspace layout (bytes, 16-aligned)
    char* w = (char*)d_ws;
    int*    perm   = (int*)(w);                  // 245760   -> 245760
    int*    rowptr = (int*)(w + 245760);         // 21600    -> 267360
    uchar*  rho8   = (uchar*)(w + 267360);       // 61440    -> 328800
    short*  wcat   = (short*)(w + 328800);       // 147456   -> 476256
    float*  bcat   = (float*)(w + 476256);       // 384      -> 476640
    short*  wout   = (short*)(w + 476640);       // 98304    -> 574944
    short*  w2t    = (short*)(w + 574944);       // 18432    -> 593376
    ushort* featb  = (ushort*)(w + 593376);      // 4194304  -> 4787680
    ushort* ybb    = (ushort*)(w + 4787680);     // 2097152  -> 6884832
    ushort* htcT   = (ushort*)(w + 6884832);     // 10936320 -> 17821152

    k0_prep<<<216, 256, 0, stream>>>(perm, rowptr, rho8, Wt_in, bt_in, W1,
                                     wcat, bcat, Wt_out, W2, wout, w2t);
    k1_mfma<<<NB * NTOK / 64, 512, 0, stream>>>(tokens, wcat, bcat, featb, ybb);
    k23_ht_conv<<<NB * NTH, 256, 0, stream>>>(ybb, perm, rowptr, w2t, htcT);
    k45_iht_out<<<NB * (NTOK / 64), 256, 0, stream>>>(htcT, rho8, W3, featb,
                                                      wout, bt_out, out);
}